// Round 15
// baseline (35.938 us; speedup 1.0000x reference)
//
#include <hip/hip_runtime.h>

// QuanvolutionSelfAttentionClassifier on MI355X — round 15: 2x TLP.
//
// Algebra (verified R1-R14): softmax over length-1 axis == 1 ->
// attn_weights == mean_embeds (rotation/entangle dead). l = c*196+p ->
// d = p&3; pixel (r,cc): d = (2*((r>>1)&1) + (cc>>1)) & 3.
//   logits[j] = lin_b[j] + sum_d M[d]*(cst[d][j] + T[d][j])
//   M[d] = a + sum_pix x*gm,  T[d][j] = sum_{pix in d} x*G[pix][j]
// Y = X·G via mfma_f32_16x16x32_bf16, split-bf16 hi/lo (AhBh+AlBh+AhBl),
// col = d*12+j; symmetric A/B k-placement; C layout col=lane&15,
// row=(lane>>4)*4+reg — numerics verified 4x (absmax 0.0156 harness floor).
//
// Elimination record: spill (R7: waves_per_eu pin), barriers (R12),
// B-gather TA pressure (R13: B->LDS, 44->31us), A-load latency depth
// (R14: depth-4 neutral -> falsified). Remaining: only 8 waves/CU (2/SIMD)
// — per-CU serial work ~39K cy barely overlaps; all pipes <15% busy.
// v15: 1024-thread blocks (16 waves, 4/SIMD), 128 blocks, still 1 block/CU;
// waves_per_eu(4,4) (VGPR budget 128 >= ~90 live). Everything else identical.

typedef __attribute__((ext_vector_type(8))) short bf16x8;
typedef __attribute__((ext_vector_type(4))) float f32x4;
typedef __attribute__((ext_vector_type(4))) unsigned int uint4v;

union BU { uint4v u; bf16x8 b; };

__device__ __forceinline__ unsigned short f2bf(float f) {
  unsigned u = __float_as_uint(f);
  unsigned r = u + 0x7FFFu + ((u >> 16) & 1u);
  return (unsigned short)(r >> 16);
}
__device__ __forceinline__ float bf2f(unsigned short h) {
  return __uint_as_float((unsigned)h << 16);
}

#define CST_F 38400   // float idx in ws (after 76800 shorts): cst[40]
#define A_F   38440   // float idx: a

// prep: B-image bf16 hi/lo, BYTE-IDENTICAL to the main kernel's LDS layout.
// i -> e=i&7, ln=(i>>3)&63, c=i>>9 (c = t*3+nt); col=(c%3)*16+(ln&15),
// k=(c/3)*32+(ln>>4)*8+e. Chunk c: hi shorts [c*1024 + ln*8 + e], lo +512.
__global__ void qsac_prep(const float* __restrict__ cw, const float* __restrict__ cb,
                          const float* __restrict__ lw, float* __restrict__ wsf) {
  unsigned short* gt = (unsigned short*)wsf;
  const int i = blockIdx.x * 256 + threadIdx.x;  // 150 x 256 = 38400
  const int e = i & 7, ln = (i >> 3) & 63, c = i >> 9;
  const int t = c / 3, nt = c - t * 3;
  const int col = nt * 16 + (ln & 15);
  const int k = t * 32 + (ln >> 4) * 8 + e;
  float val = 0.f;
  if (k < 784) {
    const int r = k / 28, cc = k - r * 28;
    const int kh = r & 1, kw = cc & 1;
    const int p = (r >> 1) * 14 + (cc >> 1);
    const int dpix = (2 * ((r >> 1) & 1) + (cc >> 1)) & 3;
    const int cd = col / 12, cj = col - cd * 12;
    if (cd == dpix) {
      const float w0 = cw[(kh << 1) + kw],     w1 = cw[4 + (kh << 1) + kw],
                  w2 = cw[8 + (kh << 1) + kw], w3 = cw[12 + (kh << 1) + kw];
      if (cj < 10)
        val = w0 * lw[cj * 784 + p]       + w1 * lw[cj * 784 + 196 + p] +
              w2 * lw[cj * 784 + 392 + p] + w3 * lw[cj * 784 + 588 + p];
      else if (cj == 10)
        val = (w0 + w1 + w2 + w3) * (1.0f / 196.0f);
    }
  }
  const unsigned short hh = f2bf(val);
  gt[c * 1024 + ln * 8 + e] = hh;
  gt[c * 1024 + 512 + ln * 8 + e] = f2bf(val - bf2f(hh));

  if (blockIdx.x == 0) {
    const int u = threadIdx.x;
    if (u < 40) {
      const int d = u / 10, j = u - (u / 10) * 10;
      const float b0 = cb[0], b1 = cb[1], b2 = cb[2], b3 = cb[3];
      float s = 0.f;
#pragma unroll 7
      for (int q = d; q < 196; q += 4)
        s += b0 * lw[j * 784 + q]       + b1 * lw[j * 784 + 196 + q] +
             b2 * lw[j * 784 + 392 + q] + b3 * lw[j * 784 + 588 + q];
      wsf[CST_F + u] = s;
    } else if (u == 40) {
      wsf[A_F] = (cb[0] + cb[1] + cb[2] + cb[3]) * 0.25f;
    }
  }
}

__global__ __launch_bounds__(1024)
__attribute__((amdgpu_waves_per_eu(4, 4))) void qsac_main(
    const float* __restrict__ x, const float* __restrict__ wsf,
    const float* __restrict__ lin_b, float* __restrict__ out) {
  // B in LDS: chunk c (=t*3+nt): hi 16B/lane at byte c*2048+lane*16, lo +1024.
  __shared__ unsigned int smemu[38400];  // 153,600 B -> 1 block/CU

  const int tid = threadIdx.x;
  const int lane = tid & 63;
  const int wid = __builtin_amdgcn_readfirstlane(tid >> 6);  // 0..15
  const int nn = lane & 15, kb = lane >> 4;
  const int sbase = blockIdx.x * 256 + wid * 16;
  const float* xrow = x + (size_t)(sbase + nn) * 784;

  // ---- B staging: pure 16B global_load_lds copy of the ws image.
  // 9600 chunks; wave-uniform LDS base (HW adds lane*16). 16 waves:
  // i=0..8 full (1024 chunks each), i=9 remainder (wid<6).
  {
    const char* wsb = (const char*)wsf;
#pragma unroll
    for (int i = 0; i < 9; ++i) {
      const int cbase = i * 1024 + wid * 64;
      __builtin_amdgcn_global_load_lds(
          (const __attribute__((address_space(1))) unsigned int*)
              (wsb + (size_t)(cbase + lane) * 16),
          (__attribute__((address_space(3))) unsigned int*)&smemu[cbase * 4],
          16, 0, 0);
    }
    if (wid < 6) {
      const int cbase = 9216 + wid * 64;
      __builtin_amdgcn_global_load_lds(
          (const __attribute__((address_space(1))) unsigned int*)
              (wsb + (size_t)(cbase + lane) * 16),
          (__attribute__((address_space(3))) unsigned int*)&smemu[cbase * 4],
          16, 0, 0);
    }
  }
  __syncthreads();  // drains vmcnt -> B image complete

  f32x4 acc[3];
#pragma unroll
  for (int nt = 0; nt < 3; ++nt) acc[nt] = (f32x4){0.f, 0.f, 0.f, 0.f};

  auto tile = [&](const float4& a, const float4& b2, int t) {
    BU bh[3], bl[3];
    const unsigned int* bb = smemu + t * 1536 + lane * 4;
#pragma unroll
    for (int nt = 0; nt < 3; ++nt) {
      bh[nt].u = *(const uint4v*)(bb + nt * 512);
      bl[nt].u = *(const uint4v*)(bb + nt * 512 + 256);
    }
    const float v[8] = {a.x, a.y, a.z, a.w, b2.x, b2.y, b2.z, b2.w};
    bf16x8 Ah, Al;
#pragma unroll
    for (int e = 0; e < 8; ++e) {
      const unsigned short hh = f2bf(v[e]);
      Ah[e] = (short)hh;
      Al[e] = (short)f2bf(v[e] - bf2f(hh));
    }
#pragma unroll
    for (int nt = 0; nt < 3; ++nt) {
      acc[nt] = __builtin_amdgcn_mfma_f32_16x16x32_bf16(Ah, bh[nt].b, acc[nt], 0, 0, 0);
      acc[nt] = __builtin_amdgcn_mfma_f32_16x16x32_bf16(Al, bh[nt].b, acc[nt], 0, 0, 0);
      acc[nt] = __builtin_amdgcn_mfma_f32_16x16x32_bf16(Ah, bl[nt].b, acc[nt], 0, 0, 0);
    }
  };

#define LD_A(PA, PB, T)                                                       \
  {                                                                           \
    const int ka = (T)*32 + kb * 8;                                           \
    const int kc = (ka < 784) ? ka : 0; /* tail: B rows >=784 are zero */     \
    PA = *(const float4*)(xrow + kc);                                         \
    PB = *(const float4*)(xrow + kc + 4);                                     \
  }

  // Depth-4 A-prefetch ring in named registers (static indexing).
  float4 a0, b0, a1, b1, a2, b2, a3, b3;
  LD_A(a0, b0, 0) LD_A(a1, b1, 1) LD_A(a2, b2, 2) LD_A(a3, b3, 3)

#pragma unroll 1
  for (int it = 0; it < 6; ++it) {
    const int t = it * 4;
    tile(a0, b0, t + 0); if (t + 4 < 25) LD_A(a0, b0, t + 4)
    tile(a1, b1, t + 1); if (t + 5 < 25) LD_A(a1, b1, t + 5)
    tile(a2, b2, t + 2); if (t + 6 < 25) LD_A(a2, b2, t + 6)
    tile(a3, b3, t + 3); if (t + 7 < 25) LD_A(a3, b3, t + 7)
  }
  tile(a0, b0, 24);

  // ---- epilogue (verified): overlay C exchange into dead B region ----
  __syncthreads();  // all waves past the loop -> B truly dead
  float* cx = (float*)smemu + wid * (16 * 52);  // 16 waves x 832 f = 53 KB
#pragma unroll
  for (int nt = 0; nt < 3; ++nt)
#pragma unroll
    for (int rg = 0; rg < 4; ++rg)
      cx[(kb * 4 + rg) * 52 + nt * 16 + nn] = acc[nt][rg];
  __builtin_amdgcn_wave_barrier();  // same-wave LDS pipe is in-order

  if (lane < 16) {
    float Y[48];
#pragma unroll
    for (int q = 0; q < 12; ++q) {
      const float4 t4 = *(const float4*)&cx[lane * 52 + q * 4];
      Y[q * 4 + 0] = t4.x; Y[q * 4 + 1] = t4.y;
      Y[q * 4 + 2] = t4.z; Y[q * 4 + 3] = t4.w;
    }
    const float a = wsf[A_F];
    float M[4];
#pragma unroll
    for (int d = 0; d < 4; ++d) M[d] = a + Y[d * 12 + 10];
    float logits[10];
#pragma unroll
    for (int j = 0; j < 10; ++j) {
      float vv = lin_b[j];
#pragma unroll
      for (int d = 0; d < 4; ++d)
        vv += M[d] * (wsf[CST_F + d * 10 + j] + Y[d * 12 + j]);
      logits[j] = vv;
    }
    float mx = logits[0];
#pragma unroll
    for (int j = 1; j < 10; ++j) mx = fmaxf(mx, logits[j]);
    float se = 0.f;
#pragma unroll
    for (int j = 0; j < 10; ++j) se += __expf(logits[j] - mx);
    const float lse = mx + __logf(se);
    float* op = out + (size_t)(sbase + lane) * 10;
#pragma unroll
    for (int j = 0; j < 10; ++j) op[j] = logits[j] - lse;
  }
#undef LD_A
}

extern "C" void kernel_launch(void* const* d_in, const int* in_sizes, int n_in,
                              void* d_out, int out_size, void* d_ws, size_t ws_size,
                              hipStream_t stream) {
  (void)n_in; (void)ws_size; (void)out_size;
  const float* x = (const float*)d_in[0];
  const float* conv_w = (const float*)d_in[1];
  const float* conv_b = (const float*)d_in[2];
  // d_in[3]/d_in[4] (rotation/entangle) are dead: softmax over length-1 == 1.
  const float* lin_w = (const float*)d_in[5];
  const float* lin_b = (const float*)d_in[6];
  float* out = (float*)d_out;
  float* wsf = (float*)d_ws;

  hipLaunchKernelGGL(qsac_prep, dim3(150), dim3(256), 0, stream,
                     conv_w, conv_b, lin_w, wsf);

  const int B = in_sizes[0] / 784;  // 32768
  const int nblk = B / 256;         // 128 blocks x 1024 threads (1 block/CU)
  hipLaunchKernelGGL(qsac_main, dim3(nblk), dim3(1024), 0, stream,
                     x, wsf, lin_b, out);
}

// Round 16
// 30.351 us; speedup vs baseline: 1.1841x; 1.1841x over previous
//
#include <hip/hip_runtime.h>

// QuanvolutionSelfAttentionClassifier on MI355X — round 16: 16 waves/CU on
// the FULL machine (K-split wave pairs).
//
// Algebra (verified R1-R15): softmax over length-1 axis == 1 ->
// attn_weights == mean_embeds (rotation/entangle dead). l = c*196+p ->
// d = p&3; pixel (r,cc): d = (2*((r>>1)&1) + (cc>>1)) & 3.
//   logits[j] = lin_b[j] + sum_d M[d]*(cst[d][j] + T[d][j])
//   M[d] = a + sum_pix x*gm,  T[d][j] = sum_{pix in d} x*G[pix][j]
// Y = X·G via mfma_f32_16x16x32_bf16, split-bf16 hi/lo (AhBh+AlBh+AhBl),
// col = d*12+j; symmetric A/B k-placement; C layout col=lane&15,
// row=(lane>>4)*4+reg — numerics verified 5x (absmax 0.0156 harness floor).
//
// R15 accidentally ran HALF the CUs (128 blocks x 1 block/CU) yet only +16%
// time -> per-CU throughput 1.72x at 16 waves/CU: TLP-bound confirmed.
// v16: 256 blocks x 1024 threads (1 block/CU, full machine). 16 waves =
// 8 strips x 2 K-halves: wave (strip, kh) computes tiles [0,12) or [12,25)
// for its strip's 16 samples; pair-reduce through dead-B LDS in epilogue.
// Same total work, 2x instruction streams/CU vs R13.

typedef __attribute__((ext_vector_type(8))) short bf16x8;
typedef __attribute__((ext_vector_type(4))) float f32x4;
typedef __attribute__((ext_vector_type(4))) unsigned int uint4v;

union BU { uint4v u; bf16x8 b; };

__device__ __forceinline__ unsigned short f2bf(float f) {
  unsigned u = __float_as_uint(f);
  unsigned r = u + 0x7FFFu + ((u >> 16) & 1u);
  return (unsigned short)(r >> 16);
}
__device__ __forceinline__ float bf2f(unsigned short h) {
  return __uint_as_float((unsigned)h << 16);
}

#define CST_F 38400   // float idx in ws (after 76800 shorts): cst[40]
#define A_F   38440   // float idx: a

// prep: B-image bf16 hi/lo, BYTE-IDENTICAL to the main kernel's LDS layout.
// i -> e=i&7, ln=(i>>3)&63, c=i>>9 (c = t*3+nt); col=(c%3)*16+(ln&15),
// k=(c/3)*32+(ln>>4)*8+e. Chunk c: hi shorts [c*1024 + ln*8 + e], lo +512.
__global__ void qsac_prep(const float* __restrict__ cw, const float* __restrict__ cb,
                          const float* __restrict__ lw, float* __restrict__ wsf) {
  unsigned short* gt = (unsigned short*)wsf;
  const int i = blockIdx.x * 256 + threadIdx.x;  // 150 x 256 = 38400
  const int e = i & 7, ln = (i >> 3) & 63, c = i >> 9;
  const int t = c / 3, nt = c - t * 3;
  const int col = nt * 16 + (ln & 15);
  const int k = t * 32 + (ln >> 4) * 8 + e;
  float val = 0.f;
  if (k < 784) {
    const int r = k / 28, cc = k - r * 28;
    const int kh = r & 1, kw = cc & 1;
    const int p = (r >> 1) * 14 + (cc >> 1);
    const int dpix = (2 * ((r >> 1) & 1) + (cc >> 1)) & 3;
    const int cd = col / 12, cj = col - cd * 12;
    if (cd == dpix) {
      const float w0 = cw[(kh << 1) + kw],     w1 = cw[4 + (kh << 1) + kw],
                  w2 = cw[8 + (kh << 1) + kw], w3 = cw[12 + (kh << 1) + kw];
      if (cj < 10)
        val = w0 * lw[cj * 784 + p]       + w1 * lw[cj * 784 + 196 + p] +
              w2 * lw[cj * 784 + 392 + p] + w3 * lw[cj * 784 + 588 + p];
      else if (cj == 10)
        val = (w0 + w1 + w2 + w3) * (1.0f / 196.0f);
    }
  }
  const unsigned short hh = f2bf(val);
  gt[c * 1024 + ln * 8 + e] = hh;
  gt[c * 1024 + 512 + ln * 8 + e] = f2bf(val - bf2f(hh));

  if (blockIdx.x == 0) {
    const int u = threadIdx.x;
    if (u < 40) {
      const int d = u / 10, j = u - (u / 10) * 10;
      const float b0 = cb[0], b1 = cb[1], b2 = cb[2], b3 = cb[3];
      float s = 0.f;
#pragma unroll 7
      for (int q = d; q < 196; q += 4)
        s += b0 * lw[j * 784 + q]       + b1 * lw[j * 784 + 196 + q] +
             b2 * lw[j * 784 + 392 + q] + b3 * lw[j * 784 + 588 + q];
      wsf[CST_F + u] = s;
    } else if (u == 40) {
      wsf[A_F] = (cb[0] + cb[1] + cb[2] + cb[3]) * 0.25f;
    }
  }
}

__global__ __launch_bounds__(1024)
__attribute__((amdgpu_waves_per_eu(4, 4))) void qsac_main(
    const float* __restrict__ x, const float* __restrict__ wsf,
    const float* __restrict__ lin_b, float* __restrict__ out) {
  // B in LDS: chunk c (=t*3+nt): hi 16B/lane at byte c*2048+lane*16, lo +1024.
  __shared__ unsigned int smemu[38400];  // 153,600 B -> 1 block/CU

  const int tid = threadIdx.x;
  const int lane = tid & 63;
  const int wid = __builtin_amdgcn_readfirstlane(tid >> 6);  // 0..15
  const int strip = wid & 7;    // 8 strips x 16 samples = 128 samples/block
  const int khalf = wid >> 3;   // 0: tiles [0,12); 1: tiles [12,25)
  const int nn = lane & 15, kb = lane >> 4;
  const int sbase = blockIdx.x * 128 + strip * 16;
  const float* xrow = x + (size_t)(sbase + nn) * 784;

  // ---- B staging: pure 16B global_load_lds copy of the ws image.
  // 9600 chunks over 16 waves; wave-uniform LDS base (HW adds lane*16).
  {
    const char* wsb = (const char*)wsf;
#pragma unroll
    for (int i = 0; i < 9; ++i) {
      const int cbase = i * 1024 + wid * 64;
      __builtin_amdgcn_global_load_lds(
          (const __attribute__((address_space(1))) unsigned int*)
              (wsb + (size_t)(cbase + lane) * 16),
          (__attribute__((address_space(3))) unsigned int*)&smemu[cbase * 4],
          16, 0, 0);
    }
    if (wid < 6) {
      const int cbase = 9216 + wid * 64;
      __builtin_amdgcn_global_load_lds(
          (const __attribute__((address_space(1))) unsigned int*)
              (wsb + (size_t)(cbase + lane) * 16),
          (__attribute__((address_space(3))) unsigned int*)&smemu[cbase * 4],
          16, 0, 0);
    }
  }
  __syncthreads();  // drains vmcnt -> B image complete

  f32x4 acc[3];
#pragma unroll
  for (int nt = 0; nt < 3; ++nt) acc[nt] = (f32x4){0.f, 0.f, 0.f, 0.f};

  auto tile = [&](const float4& a, const float4& b2, int t) {
    BU bh[3], bl[3];
    const unsigned int* bb = smemu + t * 1536 + lane * 4;
#pragma unroll
    for (int nt = 0; nt < 3; ++nt) {
      bh[nt].u = *(const uint4v*)(bb + nt * 512);
      bl[nt].u = *(const uint4v*)(bb + nt * 512 + 256);
    }
    const float v[8] = {a.x, a.y, a.z, a.w, b2.x, b2.y, b2.z, b2.w};
    bf16x8 Ah, Al;
#pragma unroll
    for (int e = 0; e < 8; ++e) {
      const unsigned short hh = f2bf(v[e]);
      Ah[e] = (short)hh;
      Al[e] = (short)f2bf(v[e] - bf2f(hh));
    }
#pragma unroll
    for (int nt = 0; nt < 3; ++nt) {
      acc[nt] = __builtin_amdgcn_mfma_f32_16x16x32_bf16(Ah, bh[nt].b, acc[nt], 0, 0, 0);
      acc[nt] = __builtin_amdgcn_mfma_f32_16x16x32_bf16(Al, bh[nt].b, acc[nt], 0, 0, 0);
      acc[nt] = __builtin_amdgcn_mfma_f32_16x16x32_bf16(Ah, bl[nt].b, acc[nt], 0, 0, 0);
    }
  };

  auto ldA = [&](int t, float4& a, float4& b2) {
    const int ka = t * 32 + kb * 8;
    const int kc = (ka < 784) ? ka : 0;  // tail: B rows >=784 are zero
    a = *(const float4*)(xrow + kc);
    b2 = *(const float4*)(xrow + kc + 4);
  };

  // K-half [t0, t1): 12 or 13 tiles; depth-1 ping-pong prefetch.
  const int t0 = khalf ? 12 : 0;
  const int t1 = khalf ? 25 : 12;
  float4 xa, xb, na, nb;
  ldA(t0, xa, xb);
#pragma unroll 1
  for (int t = t0; t < t1 - 1; ++t) {
    ldA(t + 1, na, nb);
    tile(xa, xb, t);
    xa = na; xb = nb;
  }
  tile(xa, xb, t1 - 1);

  // ---- pair-reduction + epilogue in dead-B LDS ----
  __syncthreads();  // all waves past the loop -> B truly dead
  float* red = (float*)smemu;                   // [8 strips][64 lanes][12]
  if (khalf == 1) {
#pragma unroll
    for (int nt = 0; nt < 3; ++nt)
#pragma unroll
      for (int rg = 0; rg < 4; ++rg)
        red[(strip * 64 + lane) * 12 + nt * 4 + rg] = acc[nt][rg];
  }
  __syncthreads();
  if (khalf == 0) {
#pragma unroll
    for (int nt = 0; nt < 3; ++nt)
#pragma unroll
      for (int rg = 0; rg < 4; ++rg)
        acc[nt][rg] += red[(strip * 64 + lane) * 12 + nt * 4 + rg];

    // C exchange (per-strip region after the reduction area) + finish.
    float* cx = (float*)smemu + 8192 + strip * (16 * 52);
#pragma unroll
    for (int nt = 0; nt < 3; ++nt)
#pragma unroll
      for (int rg = 0; rg < 4; ++rg)
        cx[(kb * 4 + rg) * 52 + nt * 16 + nn] = acc[nt][rg];
    __builtin_amdgcn_wave_barrier();  // same-wave LDS pipe is in-order

    if (lane < 16) {
      float Y[48];
#pragma unroll
      for (int q = 0; q < 12; ++q) {
        const float4 t4 = *(const float4*)&cx[lane * 52 + q * 4];
        Y[q * 4 + 0] = t4.x; Y[q * 4 + 1] = t4.y;
        Y[q * 4 + 2] = t4.z; Y[q * 4 + 3] = t4.w;
      }
      const float a = wsf[A_F];
      float M[4];
#pragma unroll
      for (int d = 0; d < 4; ++d) M[d] = a + Y[d * 12 + 10];
      float logits[10];
#pragma unroll
      for (int j = 0; j < 10; ++j) {
        float vv = lin_b[j];
#pragma unroll
        for (int d = 0; d < 4; ++d)
          vv += M[d] * (wsf[CST_F + d * 10 + j] + Y[d * 12 + j]);
        logits[j] = vv;
      }
      float mx = logits[0];
#pragma unroll
      for (int j = 1; j < 10; ++j) mx = fmaxf(mx, logits[j]);
      float se = 0.f;
#pragma unroll
      for (int j = 0; j < 10; ++j) se += __expf(logits[j] - mx);
      const float lse = mx + __logf(se);
      float* op = out + (size_t)(sbase + lane) * 10;
#pragma unroll
      for (int j = 0; j < 10; ++j) op[j] = logits[j] - lse;
    }
  }
}

extern "C" void kernel_launch(void* const* d_in, const int* in_sizes, int n_in,
                              void* d_out, int out_size, void* d_ws, size_t ws_size,
                              hipStream_t stream) {
  (void)n_in; (void)ws_size; (void)out_size;
  const float* x = (const float*)d_in[0];
  const float* conv_w = (const float*)d_in[1];
  const float* conv_b = (const float*)d_in[2];
  // d_in[3]/d_in[4] (rotation/entangle) are dead: softmax over length-1 == 1.
  const float* lin_w = (const float*)d_in[5];
  const float* lin_b = (const float*)d_in[6];
  float* out = (float*)d_out;
  float* wsf = (float*)d_ws;

  hipLaunchKernelGGL(qsac_prep, dim3(150), dim3(256), 0, stream,
                     conv_w, conv_b, lin_w, wsf);

  const int B = in_sizes[0] / 784;  // 32768
  const int nblk = B / 128;         // 256 blocks x 1024 threads (1 block/CU)
  hipLaunchKernelGGL(qsac_main, dim3(nblk), dim3(1024), 0, stream,
                     x, wsf, lin_b, out);
}

// Round 17
// 29.460 us; speedup vs baseline: 1.2199x; 1.0302x over previous
//
#include <hip/hip_runtime.h>

// QuanvolutionSelfAttentionClassifier on MI355X — round 17: single-bf16.
//
// Algebra (verified R1-R16): softmax over length-1 axis == 1 ->
// attn_weights == mean_embeds (rotation/entangle dead). l = c*196+p ->
// d = p&3; pixel (r,cc): d = (2*((r>>1)&1) + (cc>>1)) & 3.
//   logits[j] = lin_b[j] + sum_d M[d]*(cst[d][j] + T[d][j])
//   M[d] = a + sum_pix x*gm,  T[d][j] = sum_{pix in d} x*G[pix][j]
// Y = X·G via mfma_f32_16x16x32_bf16; col = d*12+j; symmetric A/B
// k-placement; C layout col=lane&15, row=(lane>>4)*4+reg — verified 6x.
//
// R15/R16 fit: T = F + V*work with F~25us -> per-CU work optimizations are
// secondary; shrink ALL modeled pipe costs at once via an error-budget move:
// SINGLE RNE bf16 for A and B (error ~3e-3 << 0.062 margin; was split-hi/lo).
//  - MFMA 9 -> 3 per k-step; conversion VALU ~70 -> ~30.
//  - B image 153.6 -> 76.8 KB -> 512-thread blocks at 2 blocks/CU
//    (512 blocks, 16 waves/CU kept, less barrier skew, better tail).
//  - B-reads 6 -> 3 ds_read_b128 per tile.
// Skeleton (staging, K-split pairs, reduction, epilogue) = R16 verified.

typedef __attribute__((ext_vector_type(8))) short bf16x8;
typedef __attribute__((ext_vector_type(4))) float f32x4;
typedef __attribute__((ext_vector_type(4))) unsigned int uint4v;

union BU { uint4v u; bf16x8 b; };
union AB { unsigned int u[4]; bf16x8 b; };

__device__ __forceinline__ unsigned rne16(float f) {
  const unsigned u = __float_as_uint(f);
  return (u + 0x7FFFu + ((u >> 16) & 1u)) >> 16;
}

#define CST_F 19200   // float idx in ws (after 38400 shorts): cst[40]
#define A_F   19240   // float idx: a

// prep: B-image bf16 (single plane), BYTE-IDENTICAL to main's LDS layout.
// i -> e=i&7, ln=(i>>3)&63, c=i>>9 (c = t*3+nt, 0..74);
// col=(c%3)*16+(ln&15), k=(c/3)*32+(ln>>4)*8+e. Chunk c: shorts [c*512+ln*8+e].
__global__ void qsac_prep(const float* __restrict__ cw, const float* __restrict__ cb,
                          const float* __restrict__ lw, float* __restrict__ wsf) {
  unsigned short* gt = (unsigned short*)wsf;
  const int i = blockIdx.x * 256 + threadIdx.x;  // 150 x 256 = 38400
  const int e = i & 7, ln = (i >> 3) & 63, c = i >> 9;
  const int t = c / 3, nt = c - t * 3;
  const int col = nt * 16 + (ln & 15);
  const int k = t * 32 + (ln >> 4) * 8 + e;
  float val = 0.f;
  if (k < 784) {
    const int r = k / 28, cc = k - r * 28;
    const int kh = r & 1, kw = cc & 1;
    const int p = (r >> 1) * 14 + (cc >> 1);
    const int dpix = (2 * ((r >> 1) & 1) + (cc >> 1)) & 3;
    const int cd = col / 12, cj = col - cd * 12;
    if (cd == dpix) {
      const float w0 = cw[(kh << 1) + kw],     w1 = cw[4 + (kh << 1) + kw],
                  w2 = cw[8 + (kh << 1) + kw], w3 = cw[12 + (kh << 1) + kw];
      if (cj < 10)
        val = w0 * lw[cj * 784 + p]       + w1 * lw[cj * 784 + 196 + p] +
              w2 * lw[cj * 784 + 392 + p] + w3 * lw[cj * 784 + 588 + p];
      else if (cj == 10)
        val = (w0 + w1 + w2 + w3) * (1.0f / 196.0f);
    }
  }
  gt[c * 512 + ln * 8 + e] = (unsigned short)rne16(val);

  if (blockIdx.x == 0) {
    const int u = threadIdx.x;
    if (u < 40) {
      const int d = u / 10, j = u - (u / 10) * 10;
      const float b0 = cb[0], b1 = cb[1], b2 = cb[2], b3 = cb[3];
      float s = 0.f;
#pragma unroll 7
      for (int q = d; q < 196; q += 4)
        s += b0 * lw[j * 784 + q]       + b1 * lw[j * 784 + 196 + q] +
             b2 * lw[j * 784 + 392 + q] + b3 * lw[j * 784 + 588 + q];
      wsf[CST_F + u] = s;
    } else if (u == 40) {
      wsf[A_F] = (cb[0] + cb[1] + cb[2] + cb[3]) * 0.25f;
    }
  }
}

__global__ __launch_bounds__(512)
__attribute__((amdgpu_waves_per_eu(4, 4))) void qsac_main(
    const float* __restrict__ x, const float* __restrict__ wsf,
    const float* __restrict__ lin_b, float* __restrict__ out) {
  // B in LDS: chunk c (=t*3+nt): 16B/lane at byte c*1024 + lane*16.
  __shared__ unsigned int smemu[19200];  // 76,800 B -> 2 blocks/CU

  const int tid = threadIdx.x;
  const int lane = tid & 63;
  const int wid = __builtin_amdgcn_readfirstlane(tid >> 6);  // 0..7
  const int strip = wid & 3;    // 4 strips x 16 samples = 64 samples/block
  const int khalf = wid >> 2;   // 0: tiles [0,12); 1: tiles [12,25)
  const int nn = lane & 15, kb = lane >> 4;
  const int sbase = blockIdx.x * 64 + strip * 16;
  const float* xrow = x + (size_t)(sbase + nn) * 784;

  // ---- B staging: pure 16B global_load_lds copy of the ws image.
  // 75 chunks over 8 waves; wave-uniform LDS base (HW adds lane*16).
  {
    const char* wsb = (const char*)wsf;
#pragma unroll
    for (int i = 0; i < 10; ++i) {
      const int c = i * 8 + wid;
      if (c < 75) {
        __builtin_amdgcn_global_load_lds(
            (const __attribute__((address_space(1))) unsigned int*)
                (wsb + (size_t)(c * 64 + lane) * 16),
            (__attribute__((address_space(3))) unsigned int*)&smemu[c * 256],
            16, 0, 0);
      }
    }
  }
  __syncthreads();  // drains vmcnt -> B image complete

  f32x4 acc[3];
#pragma unroll
  for (int nt = 0; nt < 3; ++nt) acc[nt] = (f32x4){0.f, 0.f, 0.f, 0.f};

  auto tile = [&](const float4& a, const float4& b2, int t) {
    BU bh[3];
    const unsigned int* bb = smemu + t * 768 + lane * 4;
#pragma unroll
    for (int nt = 0; nt < 3; ++nt) bh[nt].u = *(const uint4v*)(bb + nt * 256);
    AB Ah;
    Ah.u[0] = rne16(a.x)  | (rne16(a.y)  << 16);
    Ah.u[1] = rne16(a.z)  | (rne16(a.w)  << 16);
    Ah.u[2] = rne16(b2.x) | (rne16(b2.y) << 16);
    Ah.u[3] = rne16(b2.z) | (rne16(b2.w) << 16);
#pragma unroll
    for (int nt = 0; nt < 3; ++nt)
      acc[nt] = __builtin_amdgcn_mfma_f32_16x16x32_bf16(Ah.b, bh[nt].b, acc[nt], 0, 0, 0);
  };

  auto ldA = [&](int t, float4& a, float4& b2) {
    const int ka = t * 32 + kb * 8;
    const int kc = (ka < 784) ? ka : 0;  // tail: B rows >=784 are zero
    a = *(const float4*)(xrow + kc);
    b2 = *(const float4*)(xrow + kc + 4);
  };

  // K-half [t0, t1): depth-1 ping-pong prefetch (R14: deeper is neutral).
  const int t0 = khalf ? 12 : 0;
  const int t1 = khalf ? 25 : 12;
  float4 xa, xb, na, nb;
  ldA(t0, xa, xb);
#pragma unroll 1
  for (int t = t0; t < t1 - 1; ++t) {
    ldA(t + 1, na, nb);
    tile(xa, xb, t);
    xa = na; xb = nb;
  }
  tile(xa, xb, t1 - 1);

  // ---- pair-reduction + epilogue in dead-B LDS ----
  __syncthreads();  // all waves past the loop -> B truly dead
  float* red = (float*)smemu;                   // [4 strips][64 lanes][12]
  if (khalf == 1) {
#pragma unroll
    for (int nt = 0; nt < 3; ++nt)
#pragma unroll
      for (int rg = 0; rg < 4; ++rg)
        red[(strip * 64 + lane) * 12 + nt * 4 + rg] = acc[nt][rg];
  }
  __syncthreads();
  if (khalf == 0) {
#pragma unroll
    for (int nt = 0; nt < 3; ++nt)
#pragma unroll
      for (int rg = 0; rg < 4; ++rg)
        acc[nt][rg] += red[(strip * 64 + lane) * 12 + nt * 4 + rg];

    // C exchange (after the reduction area) + per-sample finish.
    float* cx = (float*)smemu + 3072 + strip * (16 * 52);
#pragma unroll
    for (int nt = 0; nt < 3; ++nt)
#pragma unroll
      for (int rg = 0; rg < 4; ++rg)
        cx[(kb * 4 + rg) * 52 + nt * 16 + nn] = acc[nt][rg];
    __builtin_amdgcn_wave_barrier();  // same-wave LDS pipe is in-order

    if (lane < 16) {
      float Y[48];
#pragma unroll
      for (int q = 0; q < 12; ++q) {
        const float4 t4 = *(const float4*)&cx[lane * 52 + q * 4];
        Y[q * 4 + 0] = t4.x; Y[q * 4 + 1] = t4.y;
        Y[q * 4 + 2] = t4.z; Y[q * 4 + 3] = t4.w;
      }
      const float a = wsf[A_F];
      float M[4];
#pragma unroll
      for (int d = 0; d < 4; ++d) M[d] = a + Y[d * 12 + 10];
      float logits[10];
#pragma unroll
      for (int j = 0; j < 10; ++j) {
        float vv = lin_b[j];
#pragma unroll
        for (int d = 0; d < 4; ++d)
          vv += M[d] * (wsf[CST_F + d * 10 + j] + Y[d * 12 + j]);
        logits[j] = vv;
      }
      float mx = logits[0];
#pragma unroll
      for (int j = 1; j < 10; ++j) mx = fmaxf(mx, logits[j]);
      float se = 0.f;
#pragma unroll
      for (int j = 0; j < 10; ++j) se += __expf(logits[j] - mx);
      const float lse = mx + __logf(se);
      float* op = out + (size_t)(sbase + lane) * 10;
#pragma unroll
      for (int j = 0; j < 10; ++j) op[j] = logits[j] - lse;
    }
  }
}

extern "C" void kernel_launch(void* const* d_in, const int* in_sizes, int n_in,
                              void* d_out, int out_size, void* d_ws, size_t ws_size,
                              hipStream_t stream) {
  (void)n_in; (void)ws_size; (void)out_size;
  const float* x = (const float*)d_in[0];
  const float* conv_w = (const float*)d_in[1];
  const float* conv_b = (const float*)d_in[2];
  // d_in[3]/d_in[4] (rotation/entangle) are dead: softmax over length-1 == 1.
  const float* lin_w = (const float*)d_in[5];
  const float* lin_b = (const float*)d_in[6];
  float* out = (float*)d_out;
  float* wsf = (float*)d_ws;

  hipLaunchKernelGGL(qsac_prep, dim3(150), dim3(256), 0, stream,
                     conv_w, conv_b, lin_w, wsf);

  const int B = in_sizes[0] / 784;  // 32768
  const int nblk = B / 64;          // 512 blocks x 512 threads (2 blocks/CU)
  hipLaunchKernelGGL(qsac_main, dim3(nblk), dim3(512), 0, stream,
                     x, wsf, lin_b, out);
}